// Round 17
// baseline (67.444 us; speedup 1.0000x reference)
//
#include <hip/hip_runtime.h>
#include <hip/hip_bf16.h>
#include <stdint.h>

typedef float f4 __attribute__((ext_vector_type(4)));
typedef short bf8 __attribute__((ext_vector_type(8)));
typedef uint32_t u4 __attribute__((ext_vector_type(4)));
typedef uint32_t u2 __attribute__((ext_vector_type(2)));

#define SDIM 1024
#define DDIM 64
#define NBH  32
#define KM   4
#define NT   16   // SDIM / 64

#define MB_BLK 4096    // mask: 4*1024*1024 floats / (256 thr * 4 cols/lane)
#define KB_BLK 1024    // k conv: 2,097,152 / 8 / 256
#define VT_BLK 512     // v transpose: 32 bh * 16 tiles

__device__ __forceinline__ unsigned short f2bf(float f) {
  uint32_t u = __builtin_bit_cast(uint32_t, f);
  u += 0x7fffu + ((u >> 16) & 1u);   // RNE; finite inputs
  return (unsigned short)(u >> 16);
}

#define GLOAD16(gsrc, ldst)                                                  \
  __builtin_amdgcn_global_load_lds(                                          \
      (const __attribute__((address_space(1))) unsigned int*)(gsrc),         \
      (__attribute__((address_space(3))) unsigned int*)(ldst), 16, 0, 0)

// swizzled LDS read: [row][64] bf16 tile, byte ^= (row&7)<<4
__device__ __forceinline__ bf8 lds_ld(const unsigned short* base, int row, int e0) {
  return *(const bf8*)((const char*)base + (((row * 64 + e0) * 2) ^ ((row & 7) << 4)));
}

// ---------- fused prepass: mask->bits | k fp32->bf16 | v transpose ----------
__global__ __launch_bounds__(256) void prepass(
    const float* __restrict__ k, const float* __restrict__ v,
    const float* __restrict__ mask, unsigned short* __restrict__ kb,
    unsigned short* __restrict__ vt, uint32_t* __restrict__ mb2) {
  __shared__ float tv[64][65];
  const int b = blockIdx.x;
  const int t = threadIdx.x;
  if (b < MB_BLK) {
    // mask -> transposed bit words mb2[m][c>>5][r]; f4 loads (4 cols/lane).
    int gid4 = (b * 256 + t) * 4;
    f4 x = *(const f4*)(mask + gid4);
    uint32_t bits = (x[0] > 0.5f ? 1u : 0u) | (x[1] > 0.5f ? 2u : 0u) |
                    (x[2] > 0.5f ? 4u : 0u) | (x[3] > 0.5f ? 8u : 0u);
    uint32_t wv = bits << (gid4 & 28);
    wv |= __shfl_xor(wv, 1);
    wv |= __shfl_xor(wv, 2);
    wv |= __shfl_xor(wv, 4);
    if ((t & 7) == 0) {
      int m = gid4 >> 20;
      int r = (gid4 >> 10) & 1023;
      int c = gid4 & 1023;
      mb2[m * 32768 + (c >> 5) * 1024 + r] = wv;
    }
  } else if (b < MB_BLK + KB_BLK) {       // k fp32 -> bf16
    int base = ((b - MB_BLK) * 256 + t) * 8;
    f4 a = *(const f4*)(k + base);
    f4 c = *(const f4*)(k + base + 4);
    bf8 o;
    o[0] = (short)f2bf(a[0]); o[1] = (short)f2bf(a[1]);
    o[2] = (short)f2bf(a[2]); o[3] = (short)f2bf(a[3]);
    o[4] = (short)f2bf(c[0]); o[5] = (short)f2bf(c[1]);
    o[6] = (short)f2bf(c[2]); o[7] = (short)f2bf(c[3]);
    *(bf8*)(kb + base) = o;
  } else {                                // v [bh][s][d] -> vt [bh][d][s] bf16
    int vb = b - MB_BLK - KB_BLK;
    int bh = vb >> 4;
    int s0 = (vb & 15) * 64;
    int sr = t >> 2, c0 = (t & 3) * 16;
    const float* vp = v + ((size_t)(bh * SDIM) + s0 + sr) * DDIM + c0;
#pragma unroll
    for (int i = 0; i < 4; ++i) {
      f4 x = *(const f4*)(vp + 4 * i);
#pragma unroll
      for (int j = 0; j < 4; ++j) tv[sr][c0 + 4 * i + j] = x[j];
    }
    __syncthreads();
    int d = t >> 2, sc0 = (t & 3) * 16;
    unsigned short tmp[16];
#pragma unroll
    for (int i = 0; i < 16; ++i) tmp[i] = f2bf(tv[sc0 + i][d]);
    unsigned short* op = vt + ((size_t)(bh * DDIM) + d) * SDIM + s0 + sc0;
    bf8 o0, o1;
#pragma unroll
    for (int j = 0; j < 8; ++j) { o0[j] = (short)tmp[j]; o1[j] = (short)tmp[j + 8]; }
    *(bf8*)(op) = o0;
    *(bf8*)(op + 8) = o1;
  }
}

// ---------- fused attention: pipelined single-barrier body + K-direct ----------
// 512 thr (8 waves), 64 q-rows/block, grid 512. Wave w: QK {rt=w>>1, cp=w&1};
// PV {mask rt, row-half cp}. Body t (one __syncthreads each):
//   prefetch v(t+1)->vs[(t+1)%2] (gload_lds)
//   QK(t+1): K A-frags DIRECT FROM GLOBAL kb (L2-resident, 128KB/bh shared by
//            16 blocks; wave-private contiguous 16B chunks) -> attn store +
//            exp -> e[(t+1)%2].  No k LDS buffer, no k staging vmcnt.
//   PV(t):   e[t%2] x vs[t%2] + mask words -> acc
// LDS = v x2 + e x2 = 32KB. QK(t+1) || PV(t) data-independent.
// Known-regressive (do NOT revisit): nontemporal (+17us), reg-staging (+6.5us),
// counted-vmcnt (+3.2us), BN=128 (+16.7us), runtime-indexed dbuf (+14us).
__global__ __launch_bounds__(512, 4) void attn_main(
    const float* __restrict__ qf, const unsigned short* __restrict__ kb,
    const unsigned short* __restrict__ vtg, const uint32_t* __restrict__ mb2,
    float* __restrict__ outO, float* __restrict__ attn) {
  __shared__ __align__(16) unsigned short v_s0[64 * 64];  // 8 KB
  __shared__ __align__(16) unsigned short v_s1[64 * 64];  // 8 KB
  __shared__ __align__(16) unsigned short e_s0[64 * 64];  // 8 KB
  __shared__ __align__(16) unsigned short e_s1[64 * 64];  // 8 KB => 32 KB

  const int tid = threadIdx.x;
  const int l   = tid & 63;
  const int w   = tid >> 6;      // 0..7
  const int l16 = l & 15;
  const int lg  = l >> 4;
  const int rt  = w >> 1;        // QK row-tile == PV mask
  const int cp  = w & 1;         // QK col-pair == PV row-half

  int bid = (int)blockIdx.x;
  bid = (bid & 7) * 64 + (bid >> 3);    // XCD-bijective (512 % 8 == 0)
  const int bh = bid >> 4;
  const int r0 = (bid & 15) * 64;

  // v staging: lane-linear LDS dest; source chunk pre-swizzled
  const int srow = tid >> 3;            // 0..63
  const int sd   = ((tid & 7) ^ (srow & 7)) << 3;
  const unsigned short* vsrc = vtg + ((size_t)(bh * DDIM) + srow) * SDIM + sd;  // +ct*64

  // K A-frag base: kb[bh][32cp+l16][lg*8]; per tile += 4096; row+16 = +1024
  const unsigned short* kfrag =
      kb + ((size_t)(bh * SDIM) + 32 * cp + l16) * DDIM + lg * 8;

  GLOAD16(vsrc, v_s0 + tid * 8);   // v(0)

  // persistent Q B-frags
  bf8 bq0, bq1;
  {
    const float* qp = qf + ((size_t)(bh * SDIM) + r0 + 16 * rt + l16) * DDIM + lg * 8;
    f4 a0 = *(const f4*)qp;
    f4 a1 = *(const f4*)(qp + 4);
    f4 a2 = *(const f4*)(qp + 32);
    f4 a3 = *(const f4*)(qp + 36);
#pragma unroll
    for (int j = 0; j < 4; ++j) {
      bq0[j]     = (short)f2bf(a0[j] * 0.125f);
      bq0[j + 4] = (short)f2bf(a1[j] * 0.125f);
      bq1[j]     = (short)f2bf(a2[j] * 0.125f);
      bq1[j + 4] = (short)f2bf(a3[j] * 0.125f);
    }
  }

  f4 acc[2][4] = {};
  f4 accl[2]   = {};
  bf8 ones;
#pragma unroll
  for (int b = 0; b < 8; ++b) ones[b] = (short)0x3F80;

  const uint32_t* mbase = mb2 + rt * 32768 + r0 + l16;

  uint32_t mdwA[2][2], mdwB[2][2];
#pragma unroll
  for (int mt2 = 0; mt2 < 2; ++mt2)
#pragma unroll
    for (int kt = 0; kt < 2; ++kt)
      mdwA[mt2][kt] = mbase[kt * 1024 + 32 * cp + 16 * mt2];   // tile 0

  // QK(CT): direct-global K frags -> attn store + exp -> E buffer
#define QKSTEP(CT, EN)                                                         \
  {                                                                            \
    const unsigned short* kp = kfrag + (size_t)(CT) * 4096;                    \
    bf8 ak0 = *(const bf8*)(kp);                                               \
    bf8 ak1 = *(const bf8*)(kp + 32);                                          \
    bf8 ak2 = *(const bf8*)(kp + 1024);                                        \
    bf8 ak3 = *(const bf8*)(kp + 1024 + 32);                                   \
    f4 s0 = {}, s1 = {};                                                       \
    s0 = __builtin_amdgcn_mfma_f32_16x16x32_bf16(ak0, bq0, s0, 0, 0, 0);       \
    s0 = __builtin_amdgcn_mfma_f32_16x16x32_bf16(ak1, bq1, s0, 0, 0, 0);       \
    s1 = __builtin_amdgcn_mfma_f32_16x16x32_bf16(ak2, bq0, s1, 0, 0, 0);       \
    s1 = __builtin_amdgcn_mfma_f32_16x16x32_bf16(ak3, bq1, s1, 0, 0, 0);       \
    float* arow = attn + ((size_t)(bh * SDIM) + r0 + 16 * rt + l16) * SDIM     \
                  + (CT) * 64 + 32 * cp + 4 * lg;                              \
    *(f4*)(arow) = s0;                                                         \
    *(f4*)(arow + 16) = s1;                                                    \
    const int erow = 16 * rt + l16;                                            \
    u2 ev0, ev1;                                                               \
    ev0[0] = (uint32_t)f2bf(__expf(s0[0])) | ((uint32_t)f2bf(__expf(s0[1])) << 16); \
    ev0[1] = (uint32_t)f2bf(__expf(s0[2])) | ((uint32_t)f2bf(__expf(s0[3])) << 16); \
    ev1[0] = (uint32_t)f2bf(__expf(s1[0])) | ((uint32_t)f2bf(__expf(s1[1])) << 16); \
    ev1[1] = (uint32_t)f2bf(__expf(s1[2])) | ((uint32_t)f2bf(__expf(s1[3])) << 16); \
    const int colA = 32 * cp + 4 * lg;                                         \
    *(u2*)((char*)(EN) + (((erow * 64 + colA) * 2) ^ ((erow & 7) << 4))) = ev0; \
    *(u2*)((char*)(EN) + (((erow * 64 + colA + 16) * 2) ^ ((erow & 7) << 4))) = ev1; \
  }

  QKSTEP(0, e_s0)
  __syncthreads();   // v(0) staged + e_s0 visible + mdwA ready (full drain)

  // body: prefetch v(CT+1) || QK(CT+1) || PV(CT); ONE barrier.
#define BODY(CT, VC, VW, EC, EN, MC, MN, QKF, PFV)                             \
  {                                                                            \
    if (PFV) GLOAD16(vsrc + (size_t)((CT) + 1) * 64, (VW) + tid * 8);          \
    if (QKF) QKSTEP((CT) + 1, EN)                                              \
    {                                                                          \
      bf8 af[2][2];                                                            \
      _Pragma("unroll") for (int mt2 = 0; mt2 < 2; ++mt2) {                    \
        const int row = 32 * cp + 16 * mt2 + l16;                              \
        _Pragma("unroll") for (int kt = 0; kt < 2; ++kt) {                     \
          bf8 e = lds_ld((EC), row, kt * 32 + lg * 8);                         \
          uint32_t bits = ((MC)[mt2][kt] >> (lg * 8)) & 0xffu;                 \
          u4 ew = __builtin_bit_cast(u4, e);                                   \
          _Pragma("unroll") for (int d = 0; d < 4; ++d) {                      \
            uint32_t n2 = (bits >> (2 * d)) & 3u;                              \
            uint32_t sp = (n2 * 0x8001u) & 0x00010001u;                        \
            ew[d] &= (sp << 16) - sp;                                          \
          }                                                                    \
          af[mt2][kt] = __builtin_bit_cast(bf8, ew);                           \
        }                                                                      \
        accl[mt2] = __builtin_amdgcn_mfma_f32_16x16x32_bf16(af[mt2][0], ones, accl[mt2], 0, 0, 0); \
        accl[mt2] = __builtin_amdgcn_mfma_f32_16x16x32_bf16(af[mt2][1], ones, accl[mt2], 0, 0, 0); \
      }                                                                        \
      _Pragma("unroll") for (int nt = 0; nt < 4; ++nt) {                       \
        const int dc = 16 * nt + l16;                                          \
        bf8 bv0 = lds_ld((VC), dc, lg * 8);                                    \
        bf8 bv1 = lds_ld((VC), dc, lg * 8 + 32);                               \
        _Pragma("unroll") for (int mt2 = 0; mt2 < 2; ++mt2) {                  \
          acc[mt2][nt] = __builtin_amdgcn_mfma_f32_16x16x32_bf16(af[mt2][0], bv0, acc[mt2][nt], 0, 0, 0); \
          acc[mt2][nt] = __builtin_amdgcn_mfma_f32_16x16x32_bf16(af[mt2][1], bv1, acc[mt2][nt], 0, 0, 0); \
        }                                                                      \
      }                                                                        \
    }                                                                          \
    if (QKF) {                                                                 \
      _Pragma("unroll") for (int mt2 = 0; mt2 < 2; ++mt2)                      \
        _Pragma("unroll") for (int kt = 0; kt < 2; ++kt)                       \
          (MN)[mt2][kt] = mbase[(((CT) + 1) * 2 + kt) * 1024 + 32 * cp + 16 * mt2]; \
    }                                                                          \
    __syncthreads();                                                           \
  }

  for (int ct2 = 0; ct2 < NT / 2; ++ct2) {
    const bool lastp = (ct2 == NT / 2 - 1);
    // even body t=2ct2: QK(t+1)->e1; PV(t) reads vs0,e0,mdwA
    BODY(2 * ct2,     v_s0, v_s1, e_s0, e_s1, mdwA, mdwB, true, true)
    // odd body t=2ct2+1: QK(t+1)->e0; PV(t) reads vs1,e1,mdwB
    BODY(2 * ct2 + 1, v_s1, v_s0, e_s1, e_s0, mdwB, mdwA, !lastp, !lastp)
  }
#undef BODY
#undef QKSTEP

  // epilogue: normalize by ones-MFMA row-sum
#pragma unroll
  for (int mt2 = 0; mt2 < 2; ++mt2) {
#pragma unroll
    for (int r = 0; r < 4; ++r) {
      float inv = 1.0f / accl[mt2][r];
      int row = 32 * cp + 16 * mt2 + 4 * lg + r;
      float* orow = outO + (((size_t)(rt * NBH + bh)) * SDIM + r0 + row) * DDIM + l16;
#pragma unroll
      for (int nt = 0; nt < 4; ++nt)
        orow[16 * nt] = acc[mt2][nt][r] * inv;
    }
  }
}

extern "C" void kernel_launch(void* const* d_in, const int* in_sizes, int n_in,
                              void* d_out, int out_size, void* d_ws, size_t ws_size,
                              hipStream_t stream) {
  (void)in_sizes; (void)n_in; (void)out_size; (void)ws_size;
  const float* q    = (const float*)d_in[0];
  const float* k    = (const float*)d_in[1];
  const float* v    = (const float*)d_in[2];
  const float* mask = (const float*)d_in[3];
  float* outO = (float*)d_out;
  float* attn = (float*)d_out + (size_t)KM * NBH * SDIM * DDIM;

  char* ws = (char*)d_ws;
  unsigned short* kb = (unsigned short*)ws;                 // 4 MB
  unsigned short* vt = (unsigned short*)(ws + (4u << 20));  // 4 MB
  uint32_t*       mb = (uint32_t*)(ws + (8u << 20));        // 512 KB

  prepass<<<MB_BLK + KB_BLK + VT_BLK, 256, 0, stream>>>(k, v, mask, kb, vt, mb);
  attn_main<<<NBH * 16, 512, 0, stream>>>(q, kb, vt, mb, outO, attn);
}

// Round 18
// 53.526 us; speedup vs baseline: 1.2600x; 1.2600x over previous
//
#include <hip/hip_runtime.h>
#include <hip/hip_bf16.h>
#include <stdint.h>

typedef float f4 __attribute__((ext_vector_type(4)));
typedef short bf8 __attribute__((ext_vector_type(8)));
typedef uint32_t u4 __attribute__((ext_vector_type(4)));
typedef uint32_t u2 __attribute__((ext_vector_type(2)));

#define SDIM 1024
#define DDIM 64
#define NBH  32
#define KM   4
#define NT   16   // SDIM / 64

#define MB_BLK 4096    // mask: 4*1024*1024 floats / (256 thr * 4 cols/lane)
#define KB_BLK 1024    // k conv: 2,097,152 / 8 / 256
#define VT_BLK 512     // v transpose: 32 bh * 16 tiles

__device__ __forceinline__ unsigned short f2bf(float f) {
  uint32_t u = __builtin_bit_cast(uint32_t, f);
  u += 0x7fffu + ((u >> 16) & 1u);   // RNE; finite inputs
  return (unsigned short)(u >> 16);
}

#define GLOAD16(gsrc, ldst)                                                  \
  __builtin_amdgcn_global_load_lds(                                          \
      (const __attribute__((address_space(1))) unsigned int*)(gsrc),         \
      (__attribute__((address_space(3))) unsigned int*)(ldst), 16, 0, 0)

// swizzled LDS read: [row][64] bf16 tile, byte ^= (row&7)<<4
__device__ __forceinline__ bf8 lds_ld(const unsigned short* base, int row, int e0) {
  return *(const bf8*)((const char*)base + (((row * 64 + e0) * 2) ^ ((row & 7) << 4)));
}

// ---------- fused prepass: mask->bits | k fp32->bf16 | v transpose ----------
__global__ __launch_bounds__(256) void prepass(
    const float* __restrict__ k, const float* __restrict__ v,
    const float* __restrict__ mask, unsigned short* __restrict__ kb,
    unsigned short* __restrict__ vt, uint32_t* __restrict__ mb2) {
  __shared__ float tv[64][65];
  const int b = blockIdx.x;
  const int t = threadIdx.x;
  if (b < MB_BLK) {
    // mask -> transposed bit words mb2[m][c>>5][r]; f4 loads (4 cols/lane).
    int gid4 = (b * 256 + t) * 4;
    f4 x = *(const f4*)(mask + gid4);
    uint32_t bits = (x[0] > 0.5f ? 1u : 0u) | (x[1] > 0.5f ? 2u : 0u) |
                    (x[2] > 0.5f ? 4u : 0u) | (x[3] > 0.5f ? 8u : 0u);
    uint32_t wv = bits << (gid4 & 28);
    wv |= __shfl_xor(wv, 1);
    wv |= __shfl_xor(wv, 2);
    wv |= __shfl_xor(wv, 4);
    if ((t & 7) == 0) {
      int m = gid4 >> 20;
      int r = (gid4 >> 10) & 1023;
      int c = gid4 & 1023;
      mb2[m * 32768 + (c >> 5) * 1024 + r] = wv;
    }
  } else if (b < MB_BLK + KB_BLK) {       // k fp32 -> bf16
    int base = ((b - MB_BLK) * 256 + t) * 8;
    f4 a = *(const f4*)(k + base);
    f4 c = *(const f4*)(k + base + 4);
    bf8 o;
    o[0] = (short)f2bf(a[0]); o[1] = (short)f2bf(a[1]);
    o[2] = (short)f2bf(a[2]); o[3] = (short)f2bf(a[3]);
    o[4] = (short)f2bf(c[0]); o[5] = (short)f2bf(c[1]);
    o[6] = (short)f2bf(c[2]); o[7] = (short)f2bf(c[3]);
    *(bf8*)(kb + base) = o;
  } else {                                // v [bh][s][d] -> vt [bh][d][s] bf16
    int vb = b - MB_BLK - KB_BLK;
    int bh = vb >> 4;
    int s0 = (vb & 15) * 64;
    int sr = t >> 2, c0 = (t & 3) * 16;
    const float* vp = v + ((size_t)(bh * SDIM) + s0 + sr) * DDIM + c0;
#pragma unroll
    for (int i = 0; i < 4; ++i) {
      f4 x = *(const f4*)(vp + 4 * i);
#pragma unroll
      for (int j = 0; j < 4; ++j) tv[sr][c0 + 4 * i + j] = x[j];
    }
    __syncthreads();
    int d = t >> 2, sc0 = (t & 3) * 16;
    unsigned short tmp[16];
#pragma unroll
    for (int i = 0; i < 16; ++i) tmp[i] = f2bf(tv[sc0 + i][d]);
    unsigned short* op = vt + ((size_t)(bh * DDIM) + d) * SDIM + s0 + sc0;
    bf8 o0, o1;
#pragma unroll
    for (int j = 0; j < 8; ++j) { o0[j] = (short)tmp[j]; o1[j] = (short)tmp[j + 8]; }
    *(bf8*)(op) = o0;
    *(bf8*)(op + 8) = o1;
  }
}

// ---------- fused attention: single-barrier software-pipelined body ----------
// (r16: measured best, 53.48us total.)
// 512 thr (8 waves), 64 q-rows/block, grid 512. Wave w: QK {rt=w>>1, cp=w&1};
// PV {mask rt, row-half cp}. Pipelined one tile ahead: body t does
//   prefetch k(t+2)->ks[t%2], v(t+1)->vs[(t+1)%2]      (drain: this body's bar)
//   QK(t+1):  ks[(t+1)%2] -> attn(t+1) store, exp -> e[(t+1)%2]
//   PV(t):    e[t%2] (+mask words mdw[t]) x vs[t%2] -> acc
//   mdw(t+1) loads; ONE __syncthreads().
// QK(t+1) and PV(t) are data-independent -> no intra-body serial chain; 17
// barriers total (vs 32). All buffers statically named; e_s double-buffered.
// Known-regressive (do NOT revisit): nontemporal stores (+17us), reg-staged
// T14 split (+6.5us), counted-vmcnt (+3.2us), BN=128 (+16.7us), runtime-
// indexed dbuf (+14us), K-direct-from-global (+14us: loses prefetch distance).
__global__ __launch_bounds__(512, 4) void attn_main(
    const float* __restrict__ qf, const unsigned short* __restrict__ kb,
    const unsigned short* __restrict__ vtg, const uint32_t* __restrict__ mb2,
    float* __restrict__ outO, float* __restrict__ attn) {
  __shared__ __align__(16) unsigned short k_s0[64 * 64];  // 8 KB
  __shared__ __align__(16) unsigned short k_s1[64 * 64];  // 8 KB
  __shared__ __align__(16) unsigned short v_s0[64 * 64];  // 8 KB
  __shared__ __align__(16) unsigned short v_s1[64 * 64];  // 8 KB
  __shared__ __align__(16) unsigned short e_s0[64 * 64];  // 8 KB
  __shared__ __align__(16) unsigned short e_s1[64 * 64];  // 8 KB => 48 KB

  const int tid = threadIdx.x;
  const int l   = tid & 63;
  const int w   = tid >> 6;      // 0..7
  const int l16 = l & 15;
  const int lg  = l >> 4;
  const int rt  = w >> 1;        // QK row-tile == PV mask
  const int cp  = w & 1;         // QK col-pair == PV row-half

  int bid = (int)blockIdx.x;
  bid = (bid & 7) * 64 + (bid >> 3);    // XCD-bijective (512 % 8 == 0)
  const int bh = bid >> 4;
  const int r0 = (bid & 15) * 64;

  // staging: lane-linear LDS dest; source chunk pre-swizzled
  const int srow = tid >> 3;            // 0..63
  const int sd   = ((tid & 7) ^ (srow & 7)) << 3;
  const unsigned short* ksrc = kb  + ((size_t)(bh * SDIM) + srow) * DDIM + sd;  // +ct*4096
  const unsigned short* vsrc = vtg + ((size_t)(bh * DDIM) + srow) * SDIM + sd;  // +ct*64

  // prologue staging: k(0)->ks0, k(1)->ks1, v(0)->vs0
  GLOAD16(ksrc,        k_s0 + tid * 8);
  GLOAD16(ksrc + 4096, k_s1 + tid * 8);
  GLOAD16(vsrc,        v_s0 + tid * 8);

  // persistent Q B-frags
  bf8 bq0, bq1;
  {
    const float* qp = qf + ((size_t)(bh * SDIM) + r0 + 16 * rt + l16) * DDIM + lg * 8;
    f4 a0 = *(const f4*)qp;
    f4 a1 = *(const f4*)(qp + 4);
    f4 a2 = *(const f4*)(qp + 32);
    f4 a3 = *(const f4*)(qp + 36);
#pragma unroll
    for (int j = 0; j < 4; ++j) {
      bq0[j]     = (short)f2bf(a0[j] * 0.125f);
      bq0[j + 4] = (short)f2bf(a1[j] * 0.125f);
      bq1[j]     = (short)f2bf(a2[j] * 0.125f);
      bq1[j + 4] = (short)f2bf(a3[j] * 0.125f);
    }
  }

  f4 acc[2][4] = {};
  f4 accl[2]   = {};
  bf8 ones;
#pragma unroll
  for (int b = 0; b < 8; ++b) ones[b] = (short)0x3F80;

  const uint32_t* mbase = mb2 + rt * 32768 + r0 + l16;

  uint32_t mdwA[2][2], mdwB[2][2];
#pragma unroll
  for (int mt2 = 0; mt2 < 2; ++mt2)
#pragma unroll
    for (int kt = 0; kt < 2; ++kt)
      mdwA[mt2][kt] = mbase[kt * 1024 + 32 * cp + 16 * mt2];   // tile 0

  __syncthreads();   // k0,k1,v0 staged + mdwA ready (full drain)

  // QK(CT): ks -> attn store + exp -> E buffer
#define QKSTEP(CT, KN, EN)                                                     \
  {                                                                            \
    const int kc0 = 32 * cp + l16;                                             \
    bf8 ak0 = lds_ld((KN), kc0, lg * 8);                                       \
    bf8 ak1 = lds_ld((KN), kc0, lg * 8 + 32);                                  \
    bf8 ak2 = lds_ld((KN), kc0 + 16, lg * 8);                                  \
    bf8 ak3 = lds_ld((KN), kc0 + 16, lg * 8 + 32);                             \
    f4 s0 = {}, s1 = {};                                                       \
    s0 = __builtin_amdgcn_mfma_f32_16x16x32_bf16(ak0, bq0, s0, 0, 0, 0);       \
    s0 = __builtin_amdgcn_mfma_f32_16x16x32_bf16(ak1, bq1, s0, 0, 0, 0);       \
    s1 = __builtin_amdgcn_mfma_f32_16x16x32_bf16(ak2, bq0, s1, 0, 0, 0);       \
    s1 = __builtin_amdgcn_mfma_f32_16x16x32_bf16(ak3, bq1, s1, 0, 0, 0);       \
    float* arow = attn + ((size_t)(bh * SDIM) + r0 + 16 * rt + l16) * SDIM     \
                  + (CT) * 64 + 32 * cp + 4 * lg;                              \
    *(f4*)(arow) = s0;                                                         \
    *(f4*)(arow + 16) = s1;                                                    \
    const int erow = 16 * rt + l16;                                            \
    u2 ev0, ev1;                                                               \
    ev0[0] = (uint32_t)f2bf(__expf(s0[0])) | ((uint32_t)f2bf(__expf(s0[1])) << 16); \
    ev0[1] = (uint32_t)f2bf(__expf(s0[2])) | ((uint32_t)f2bf(__expf(s0[3])) << 16); \
    ev1[0] = (uint32_t)f2bf(__expf(s1[0])) | ((uint32_t)f2bf(__expf(s1[1])) << 16); \
    ev1[1] = (uint32_t)f2bf(__expf(s1[2])) | ((uint32_t)f2bf(__expf(s1[3])) << 16); \
    const int colA = 32 * cp + 4 * lg;                                         \
    *(u2*)((char*)(EN) + (((erow * 64 + colA) * 2) ^ ((erow & 7) << 4))) = ev0; \
    *(u2*)((char*)(EN) + (((erow * 64 + colA + 16) * 2) ^ ((erow & 7) << 4))) = ev1; \
  }

  QKSTEP(0, k_s0, e_s0)
  asm volatile("s_waitcnt lgkmcnt(0)\n\ts_barrier" ::: "memory");  // e_s0 visible

  // body: QK(CT+1) || PV(CT); one barrier.
#define BODY(CT, KN, VC, KW, VW, EC, EN, MC, MN, QKF, PFK, PFV)                \
  {                                                                            \
    if (PFK) GLOAD16(ksrc + (size_t)((CT) + 2) * 4096, (KW) + tid * 8);        \
    if (PFV) GLOAD16(vsrc + (size_t)((CT) + 1) * 64, (VW) + tid * 8);          \
    if (QKF) QKSTEP((CT) + 1, KN, EN)                                          \
    {                                                                          \
      bf8 af[2][2];                                                            \
      _Pragma("unroll") for (int mt2 = 0; mt2 < 2; ++mt2) {                    \
        const int row = 32 * cp + 16 * mt2 + l16;                              \
        _Pragma("unroll") for (int kt = 0; kt < 2; ++kt) {                     \
          bf8 e = lds_ld((EC), row, kt * 32 + lg * 8);                         \
          uint32_t bits = ((MC)[mt2][kt] >> (lg * 8)) & 0xffu;                 \
          u4 ew = __builtin_bit_cast(u4, e);                                   \
          _Pragma("unroll") for (int d = 0; d < 4; ++d) {                      \
            uint32_t n2 = (bits >> (2 * d)) & 3u;                              \
            uint32_t sp = (n2 * 0x8001u) & 0x00010001u;                        \
            ew[d] &= (sp << 16) - sp;                                          \
          }                                                                    \
          af[mt2][kt] = __builtin_bit_cast(bf8, ew);                           \
        }                                                                      \
        accl[mt2] = __builtin_amdgcn_mfma_f32_16x16x32_bf16(af[mt2][0], ones, accl[mt2], 0, 0, 0); \
        accl[mt2] = __builtin_amdgcn_mfma_f32_16x16x32_bf16(af[mt2][1], ones, accl[mt2], 0, 0, 0); \
      }                                                                        \
      _Pragma("unroll") for (int nt = 0; nt < 4; ++nt) {                       \
        const int dc = 16 * nt + l16;                                          \
        bf8 bv0 = lds_ld((VC), dc, lg * 8);                                    \
        bf8 bv1 = lds_ld((VC), dc, lg * 8 + 32);                               \
        _Pragma("unroll") for (int mt2 = 0; mt2 < 2; ++mt2) {                  \
          acc[mt2][nt] = __builtin_amdgcn_mfma_f32_16x16x32_bf16(af[mt2][0], bv0, acc[mt2][nt], 0, 0, 0); \
          acc[mt2][nt] = __builtin_amdgcn_mfma_f32_16x16x32_bf16(af[mt2][1], bv1, acc[mt2][nt], 0, 0, 0); \
        }                                                                      \
      }                                                                        \
    }                                                                          \
    if (QKF) {                                                                 \
      _Pragma("unroll") for (int mt2 = 0; mt2 < 2; ++mt2)                      \
        _Pragma("unroll") for (int kt = 0; kt < 2; ++kt)                       \
          (MN)[mt2][kt] = mbase[(((CT) + 1) * 2 + kt) * 1024 + 32 * cp + 16 * mt2]; \
    }                                                                          \
    __syncthreads();                                                           \
  }

  for (int ct2 = 0; ct2 < NT / 2; ++ct2) {
    const bool lastp = (ct2 == NT / 2 - 1);
    // even body t=2ct2: QK(t+1) reads ks1, writes e1; PV(t) reads vs0,e0,mdwA
    BODY(2 * ct2,     k_s1, v_s0, k_s0, v_s1, e_s0, e_s1, mdwA, mdwB,
         true, !lastp, true)
    // odd body t=2ct2+1: QK(t+1) reads ks0, writes e0; PV(t) reads vs1,e1,mdwB
    BODY(2 * ct2 + 1, k_s0, v_s1, k_s1, v_s0, e_s1, e_s0, mdwB, mdwA,
         !lastp, !lastp, !lastp)
  }
#undef BODY
#undef QKSTEP

  // epilogue: normalize by ones-MFMA row-sum
#pragma unroll
  for (int mt2 = 0; mt2 < 2; ++mt2) {
#pragma unroll
    for (int r = 0; r < 4; ++r) {
      float inv = 1.0f / accl[mt2][r];
      int row = 32 * cp + 16 * mt2 + 4 * lg + r;
      float* orow = outO + (((size_t)(rt * NBH + bh)) * SDIM + r0 + row) * DDIM + l16;
#pragma unroll
      for (int nt = 0; nt < 4; ++nt)
        orow[16 * nt] = acc[mt2][nt][r] * inv;
    }
  }
}

extern "C" void kernel_launch(void* const* d_in, const int* in_sizes, int n_in,
                              void* d_out, int out_size, void* d_ws, size_t ws_size,
                              hipStream_t stream) {
  (void)in_sizes; (void)n_in; (void)out_size; (void)ws_size;
  const float* q    = (const float*)d_in[0];
  const float* k    = (const float*)d_in[1];
  const float* v    = (const float*)d_in[2];
  const float* mask = (const float*)d_in[3];
  float* outO = (float*)d_out;
  float* attn = (float*)d_out + (size_t)KM * NBH * SDIM * DDIM;

  char* ws = (char*)d_ws;
  unsigned short* kb = (unsigned short*)ws;                 // 4 MB
  unsigned short* vt = (unsigned short*)(ws + (4u << 20));  // 4 MB
  uint32_t*       mb = (uint32_t*)(ws + (8u << 20));        // 512 KB

  prepass<<<MB_BLK + KB_BLK + VT_BLK, 256, 0, stream>>>(k, v, mask, kb, vt, mb);
  attn_main<<<NBH * 16, 512, 0, stream>>>(q, kb, vt, mb, outO, attn);
}

// Round 20
// 53.255 us; speedup vs baseline: 1.2664x; 1.0051x over previous
//
#include <hip/hip_runtime.h>
#include <hip/hip_bf16.h>
#include <stdint.h>

typedef float f4 __attribute__((ext_vector_type(4)));
typedef short bf8 __attribute__((ext_vector_type(8)));
typedef uint32_t u4 __attribute__((ext_vector_type(4)));
typedef uint32_t u2 __attribute__((ext_vector_type(2)));

#define SDIM 1024
#define DDIM 64
#define NBH  32
#define KM   4
#define NT   16   // SDIM / 64

#define MB_BLK 4096    // mask: 4*1024*1024 floats / (256 thr * 4 cols/lane)
#define KB_BLK 1024    // k conv: 2,097,152 / 8 / 256
#define VT_BLK 512     // v transpose: 32 bh * 16 tiles

__device__ __forceinline__ unsigned short f2bf(float f) {
  uint32_t u = __builtin_bit_cast(uint32_t, f);
  u += 0x7fffu + ((u >> 16) & 1u);   // RNE; finite inputs
  return (unsigned short)(u >> 16);
}

#define GLOAD16(gsrc, ldst)                                                  \
  __builtin_amdgcn_global_load_lds(                                          \
      (const __attribute__((address_space(1))) unsigned int*)(gsrc),         \
      (__attribute__((address_space(3))) unsigned int*)(ldst), 16, 0, 0)

// swizzled LDS read: [row][64] bf16 tile, byte ^= (row&7)<<4
__device__ __forceinline__ bf8 lds_ld(const unsigned short* base, int row, int e0) {
  return *(const bf8*)((const char*)base + (((row * 64 + e0) * 2) ^ ((row & 7) << 4)));
}

// ---------- fused prepass: mask->bits | k fp32->bf16 | v transpose ----------
__global__ __launch_bounds__(256) void prepass(
    const float* __restrict__ k, const float* __restrict__ v,
    const float* __restrict__ mask, unsigned short* __restrict__ kb,
    unsigned short* __restrict__ vt, uint32_t* __restrict__ mb2) {
  __shared__ float tv[64][65];
  const int b = blockIdx.x;
  const int t = threadIdx.x;
  if (b < MB_BLK) {
    // mask -> transposed bit words mb2[m][c>>5][r]; f4 loads (4 cols/lane).
    int gid4 = (b * 256 + t) * 4;
    f4 x = *(const f4*)(mask + gid4);
    uint32_t bits = (x[0] > 0.5f ? 1u : 0u) | (x[1] > 0.5f ? 2u : 0u) |
                    (x[2] > 0.5f ? 4u : 0u) | (x[3] > 0.5f ? 8u : 0u);
    uint32_t wv = bits << (gid4 & 28);
    wv |= __shfl_xor(wv, 1);
    wv |= __shfl_xor(wv, 2);
    wv |= __shfl_xor(wv, 4);
    if ((t & 7) == 0) {
      int m = gid4 >> 20;
      int r = (gid4 >> 10) & 1023;
      int c = gid4 & 1023;
      mb2[m * 32768 + (c >> 5) * 1024 + r] = wv;
    }
  } else if (b < MB_BLK + KB_BLK) {       // k fp32 -> bf16
    int base = ((b - MB_BLK) * 256 + t) * 8;
    f4 a = *(const f4*)(k + base);
    f4 c = *(const f4*)(k + base + 4);
    bf8 o;
    o[0] = (short)f2bf(a[0]); o[1] = (short)f2bf(a[1]);
    o[2] = (short)f2bf(a[2]); o[3] = (short)f2bf(a[3]);
    o[4] = (short)f2bf(c[0]); o[5] = (short)f2bf(c[1]);
    o[6] = (short)f2bf(c[2]); o[7] = (short)f2bf(c[3]);
    *(bf8*)(kb + base) = o;
  } else {                                // v [bh][s][d] -> vt [bh][d][s] bf16
    int vb = b - MB_BLK - KB_BLK;
    int bh = vb >> 4;
    int s0 = (vb & 15) * 64;
    int sr = t >> 2, c0 = (t & 3) * 16;
    const float* vp = v + ((size_t)(bh * SDIM) + s0 + sr) * DDIM + c0;
#pragma unroll
    for (int i = 0; i < 4; ++i) {
      f4 x = *(const f4*)(vp + 4 * i);
#pragma unroll
      for (int j = 0; j < 4; ++j) tv[sr][c0 + 4 * i + j] = x[j];
    }
    __syncthreads();
    int d = t >> 2, sc0 = (t & 3) * 16;
    unsigned short tmp[16];
#pragma unroll
    for (int i = 0; i < 16; ++i) tmp[i] = f2bf(tv[sc0 + i][d]);
    unsigned short* op = vt + ((size_t)(bh * DDIM) + d) * SDIM + s0 + sc0;
    bf8 o0, o1;
#pragma unroll
    for (int j = 0; j < 8; ++j) { o0[j] = (short)tmp[j]; o1[j] = (short)tmp[j + 8]; }
    *(bf8*)(op) = o0;
    *(bf8*)(op + 8) = o1;
  }
}

// ---------- fused attention: single-barrier software-pipelined body ----------
// (r16/r18: measured best, 53.5us total, reproduced twice.)
// 512 thr (8 waves), 64 q-rows/block, grid 512. Wave w: QK {rt=w>>1, cp=w&1};
// PV {mask rt, row-half cp}. Pipelined one tile ahead: body t does
//   prefetch k(t+2)->ks[t%2], v(t+1)->vs[(t+1)%2]      (drain: this body's bar)
//   QK(t+1):  ks[(t+1)%2] -> attn(t+1) store, exp -> e[(t+1)%2]
//   PV(t):    e[t%2] (+mask words mdw[t]) x vs[t%2] -> acc
//   mdw(t+1) loads; ONE __syncthreads().
// QK(t+1) and PV(t) are data-independent -> no intra-body serial chain; 17
// barriers total (vs 32). All buffers statically named; e_s double-buffered.
// Known-regressive (do NOT revisit): nontemporal stores (+17us), reg-staged
// T14 split (+6.5us), counted-vmcnt (+3.2us), BN=128 (+16.7us), runtime-
// indexed dbuf (+14us), K-direct-from-global (+14us: loses prefetch distance),
// cooperative prepass fusion (launch silently fails on this harness).
__global__ __launch_bounds__(512, 4) void attn_main(
    const float* __restrict__ qf, const unsigned short* __restrict__ kb,
    const unsigned short* __restrict__ vtg, const uint32_t* __restrict__ mb2,
    float* __restrict__ outO, float* __restrict__ attn) {
  __shared__ __align__(16) unsigned short k_s0[64 * 64];  // 8 KB
  __shared__ __align__(16) unsigned short k_s1[64 * 64];  // 8 KB
  __shared__ __align__(16) unsigned short v_s0[64 * 64];  // 8 KB
  __shared__ __align__(16) unsigned short v_s1[64 * 64];  // 8 KB
  __shared__ __align__(16) unsigned short e_s0[64 * 64];  // 8 KB
  __shared__ __align__(16) unsigned short e_s1[64 * 64];  // 8 KB => 48 KB

  const int tid = threadIdx.x;
  const int l   = tid & 63;
  const int w   = tid >> 6;      // 0..7
  const int l16 = l & 15;
  const int lg  = l >> 4;
  const int rt  = w >> 1;        // QK row-tile == PV mask
  const int cp  = w & 1;         // QK col-pair == PV row-half

  int bid = (int)blockIdx.x;
  bid = (bid & 7) * 64 + (bid >> 3);    // XCD-bijective (512 % 8 == 0)
  const int bh = bid >> 4;
  const int r0 = (bid & 15) * 64;

  // staging: lane-linear LDS dest; source chunk pre-swizzled
  const int srow = tid >> 3;            // 0..63
  const int sd   = ((tid & 7) ^ (srow & 7)) << 3;
  const unsigned short* ksrc = kb  + ((size_t)(bh * SDIM) + srow) * DDIM + sd;  // +ct*4096
  const unsigned short* vsrc = vtg + ((size_t)(bh * DDIM) + srow) * SDIM + sd;  // +ct*64

  // prologue staging: k(0)->ks0, k(1)->ks1, v(0)->vs0
  GLOAD16(ksrc,        k_s0 + tid * 8);
  GLOAD16(ksrc + 4096, k_s1 + tid * 8);
  GLOAD16(vsrc,        v_s0 + tid * 8);

  // persistent Q B-frags
  bf8 bq0, bq1;
  {
    const float* qp = qf + ((size_t)(bh * SDIM) + r0 + 16 * rt + l16) * DDIM + lg * 8;
    f4 a0 = *(const f4*)qp;
    f4 a1 = *(const f4*)(qp + 4);
    f4 a2 = *(const f4*)(qp + 32);
    f4 a3 = *(const f4*)(qp + 36);
#pragma unroll
    for (int j = 0; j < 4; ++j) {
      bq0[j]     = (short)f2bf(a0[j] * 0.125f);
      bq0[j + 4] = (short)f2bf(a1[j] * 0.125f);
      bq1[j]     = (short)f2bf(a2[j] * 0.125f);
      bq1[j + 4] = (short)f2bf(a3[j] * 0.125f);
    }
  }

  f4 acc[2][4] = {};
  f4 accl[2]   = {};
  bf8 ones;
#pragma unroll
  for (int b = 0; b < 8; ++b) ones[b] = (short)0x3F80;

  const uint32_t* mbase = mb2 + rt * 32768 + r0 + l16;

  uint32_t mdwA[2][2], mdwB[2][2];
#pragma unroll
  for (int mt2 = 0; mt2 < 2; ++mt2)
#pragma unroll
    for (int kt = 0; kt < 2; ++kt)
      mdwA[mt2][kt] = mbase[kt * 1024 + 32 * cp + 16 * mt2];   // tile 0

  __syncthreads();   // k0,k1,v0 staged + mdwA ready (full drain)

  // QK(CT): ks -> attn store + exp -> E buffer
#define QKSTEP(CT, KN, EN)                                                     \
  {                                                                            \
    const int kc0 = 32 * cp + l16;                                             \
    bf8 ak0 = lds_ld((KN), kc0, lg * 8);                                       \
    bf8 ak1 = lds_ld((KN), kc0, lg * 8 + 32);                                  \
    bf8 ak2 = lds_ld((KN), kc0 + 16, lg * 8);                                  \
    bf8 ak3 = lds_ld((KN), kc0 + 16, lg * 8 + 32);                             \
    f4 s0 = {}, s1 = {};                                                       \
    s0 = __builtin_amdgcn_mfma_f32_16x16x32_bf16(ak0, bq0, s0, 0, 0, 0);       \
    s0 = __builtin_amdgcn_mfma_f32_16x16x32_bf16(ak1, bq1, s0, 0, 0, 0);       \
    s1 = __builtin_amdgcn_mfma_f32_16x16x32_bf16(ak2, bq0, s1, 0, 0, 0);       \
    s1 = __builtin_amdgcn_mfma_f32_16x16x32_bf16(ak3, bq1, s1, 0, 0, 0);       \
    float* arow = attn + ((size_t)(bh * SDIM) + r0 + 16 * rt + l16) * SDIM     \
                  + (CT) * 64 + 32 * cp + 4 * lg;                              \
    *(f4*)(arow) = s0;                                                         \
    *(f4*)(arow + 16) = s1;                                                    \
    const int erow = 16 * rt + l16;                                            \
    u2 ev0, ev1;                                                               \
    ev0[0] = (uint32_t)f2bf(__expf(s0[0])) | ((uint32_t)f2bf(__expf(s0[1])) << 16); \
    ev0[1] = (uint32_t)f2bf(__expf(s0[2])) | ((uint32_t)f2bf(__expf(s0[3])) << 16); \
    ev1[0] = (uint32_t)f2bf(__expf(s1[0])) | ((uint32_t)f2bf(__expf(s1[1])) << 16); \
    ev1[1] = (uint32_t)f2bf(__expf(s1[2])) | ((uint32_t)f2bf(__expf(s1[3])) << 16); \
    const int colA = 32 * cp + 4 * lg;                                         \
    *(u2*)((char*)(EN) + (((erow * 64 + colA) * 2) ^ ((erow & 7) << 4))) = ev0; \
    *(u2*)((char*)(EN) + (((erow * 64 + colA + 16) * 2) ^ ((erow & 7) << 4))) = ev1; \
  }

  QKSTEP(0, k_s0, e_s0)
  asm volatile("s_waitcnt lgkmcnt(0)\n\ts_barrier" ::: "memory");  // e_s0 visible

  // body: QK(CT+1) || PV(CT); one barrier.
#define BODY(CT, KN, VC, KW, VW, EC, EN, MC, MN, QKF, PFK, PFV)                \
  {                                                                            \
    if (PFK) GLOAD16(ksrc + (size_t)((CT) + 2) * 4096, (KW) + tid * 8);        \
    if (PFV) GLOAD16(vsrc + (size_t)((CT) + 1) * 64, (VW) + tid * 8);          \
    if (QKF) QKSTEP((CT) + 1, KN, EN)                                          \
    {                                                                          \
      bf8 af[2][2];                                                            \
      _Pragma("unroll") for (int mt2 = 0; mt2 < 2; ++mt2) {                    \
        const int row = 32 * cp + 16 * mt2 + l16;                              \
        _Pragma("unroll") for (int kt = 0; kt < 2; ++kt) {                     \
          bf8 e = lds_ld((EC), row, kt * 32 + lg * 8);                         \
          uint32_t bits = ((MC)[mt2][kt] >> (lg * 8)) & 0xffu;                 \
          u4 ew = __builtin_bit_cast(u4, e);                                   \
          _Pragma("unroll") for (int d = 0; d < 4; ++d) {                      \
            uint32_t n2 = (bits >> (2 * d)) & 3u;                              \
            uint32_t sp = (n2 * 0x8001u) & 0x00010001u;                        \
            ew[d] &= (sp << 16) - sp;                                          \
          }                                                                    \
          af[mt2][kt] = __builtin_bit_cast(bf8, ew);                           \
        }                                                                      \
        accl[mt2] = __builtin_amdgcn_mfma_f32_16x16x32_bf16(af[mt2][0], ones, accl[mt2], 0, 0, 0); \
        accl[mt2] = __builtin_amdgcn_mfma_f32_16x16x32_bf16(af[mt2][1], ones, accl[mt2], 0, 0, 0); \
      }                                                                        \
      _Pragma("unroll") for (int nt = 0; nt < 4; ++nt) {                       \
        const int dc = 16 * nt + l16;                                          \
        bf8 bv0 = lds_ld((VC), dc, lg * 8);                                    \
        bf8 bv1 = lds_ld((VC), dc, lg * 8 + 32);                               \
        _Pragma("unroll") for (int mt2 = 0; mt2 < 2; ++mt2) {                  \
          acc[mt2][nt] = __builtin_amdgcn_mfma_f32_16x16x32_bf16(af[mt2][0], bv0, acc[mt2][nt], 0, 0, 0); \
          acc[mt2][nt] = __builtin_amdgcn_mfma_f32_16x16x32_bf16(af[mt2][1], bv1, acc[mt2][nt], 0, 0, 0); \
        }                                                                      \
      }                                                                        \
    }                                                                          \
    if (QKF) {                                                                 \
      _Pragma("unroll") for (int mt2 = 0; mt2 < 2; ++mt2)                      \
        _Pragma("unroll") for (int kt = 0; kt < 2; ++kt)                       \
          (MN)[mt2][kt] = mbase[(((CT) + 1) * 2 + kt) * 1024 + 32 * cp + 16 * mt2]; \
    }                                                                          \
    __syncthreads();                                                           \
  }

  for (int ct2 = 0; ct2 < NT / 2; ++ct2) {
    const bool lastp = (ct2 == NT / 2 - 1);
    // even body t=2ct2: QK(t+1) reads ks1, writes e1; PV(t) reads vs0,e0,mdwA
    BODY(2 * ct2,     k_s1, v_s0, k_s0, v_s1, e_s0, e_s1, mdwA, mdwB,
         true, !lastp, true)
    // odd body t=2ct2+1: QK(t+1) reads ks0, writes e0; PV(t) reads vs1,e1,mdwB
    BODY(2 * ct2 + 1, k_s0, v_s1, k_s1, v_s0, e_s1, e_s0, mdwB, mdwA,
         !lastp, !lastp, !lastp)
  }
#undef BODY
#undef QKSTEP

  // epilogue: normalize by ones-MFMA row-sum
#pragma unroll
  for (int mt2 = 0; mt2 < 2; ++mt2) {
#pragma unroll
    for (int r = 0; r < 4; ++r) {
      float inv = 1.0f / accl[mt2][r];
      int row = 32 * cp + 16 * mt2 + 4 * lg + r;
      float* orow = outO + (((size_t)(rt * NBH + bh)) * SDIM + r0 + row) * DDIM + l16;
#pragma unroll
      for (int nt = 0; nt < 4; ++nt)
        orow[16 * nt] = acc[mt2][nt][r] * inv;
    }
  }
}

extern "C" void kernel_launch(void* const* d_in, const int* in_sizes, int n_in,
                              void* d_out, int out_size, void* d_ws, size_t ws_size,
                              hipStream_t stream) {
  (void)in_sizes; (void)n_in; (void)out_size; (void)ws_size;
  const float* q    = (const float*)d_in[0];
  const float* k    = (const float*)d_in[1];
  const float* v    = (const float*)d_in[2];
  const float* mask = (const float*)d_in[3];
  float* outO = (float*)d_out;
  float* attn = (float*)d_out + (size_t)KM * NBH * SDIM * DDIM;

  char* ws = (char*)d_ws;
  unsigned short* kb = (unsigned short*)ws;                 // 4 MB
  unsigned short* vt = (unsigned short*)(ws + (4u << 20));  // 4 MB
  uint32_t*       mb = (uint32_t*)(ws + (8u << 20));        // 512 KB

  prepass<<<MB_BLK + KB_BLK + VT_BLK, 256, 0, stream>>>(k, v, mask, kb, vt, mb);
  attn_main<<<NBH * 16, 512, 0, stream>>>(q, kb, vt, mb, outO, attn);
}